// Round 5
// baseline (287.191 us; speedup 1.0000x reference)
//
#include <hip/hip_runtime.h>
#include <cstdint>

// Multihead self-attention, B=2 S=2048 E=1024 H=16 D=64.
// HARNESS CONTRACT (round-5 correction): inputs are FP32 (per reference
// setup_inputs dtypes), output is FP32. Internal compute: bf16 MFMA, fp32 accum.
// Pipeline: cvt x -> bf16; transpose+cvt weights -> bf16; QKV GEMM (bf16 out);
// V^T repack; flash attention; out GEMM (fp32 out).

typedef __bf16 bf16;
typedef __bf16 bf16x4 __attribute__((ext_vector_type(4)));
typedef __bf16 bf16x8 __attribute__((ext_vector_type(8)));
typedef float floatx4 __attribute__((ext_vector_type(4)));
typedef uint32_t u32;

#define B_ 2
#define S_ 2048
#define E_ 1024
#define H_ 16
#define D_ 64

// async global->LDS, 16B per lane. LDS dest = wave-uniform base + lane*16.
__device__ __forceinline__ void async16(const void* g, const void* l) {
  __builtin_amdgcn_global_load_lds(
      (u32 __attribute__((address_space(1)))*)g,
      (u32 __attribute__((address_space(3)))*)l,
      16, 0, 0);
}

// ---------------------------------------------------------------------------
// fp32 -> bf16 elementwise convert (n must be multiple of 4)
// ---------------------------------------------------------------------------
__global__ __launch_bounds__(256) void cvt_f32_bf16(
    bf16* __restrict__ dst, const float* __restrict__ src, int n4) {
  const int i = blockIdx.x * 256 + threadIdx.x;
  if (i >= n4) return;
  floatx4 v = ((const floatx4*)src)[i];
  bf16x4 o;
#pragma unroll
  for (int e = 0; e < 4; ++e) o[e] = (bf16)v[e];
  ((bf16x4*)dst)[i] = o;
}

// ---------------------------------------------------------------------------
// fp32 transpose+convert: dst[C x R] (bf16) = src[R x C]^T (fp32)
// ---------------------------------------------------------------------------
__global__ __launch_bounds__(256) void transpose_f32_bf16(
    bf16* __restrict__ dst, const float* __restrict__ src, int R, int C) {
  __shared__ float t[32][33];
  const int tx = threadIdx.x & 31, ty = threadIdx.x >> 5;  // 32 x 8
  const int c0 = blockIdx.x * 32, r0 = blockIdx.y * 32;
#pragma unroll
  for (int j = 0; j < 4; ++j)
    t[ty + 8 * j][tx] = src[(size_t)(r0 + ty + 8 * j) * C + c0 + tx];
  __syncthreads();
#pragma unroll
  for (int j = 0; j < 4; ++j)
    dst[(size_t)(c0 + ty + 8 * j) * R + r0 + tx] = (bf16)t[tx][ty + 8 * j];
}

// ---------------------------------------------------------------------------
// V^T repack: vt[(bh*64 + d)*2048 + s] = qkv[(b*2048+s)*3072 + 2048 + h*64 + d]
// ---------------------------------------------------------------------------
__global__ __launch_bounds__(256) void vt_repack(
    bf16* __restrict__ vt, const bf16* __restrict__ qkv) {
  __shared__ bf16 t[32][33];
  const int tx = threadIdx.x & 31, ty = threadIdx.x >> 5;
  const int d0 = blockIdx.x * 32, s0 = blockIdx.y * 32, bh = blockIdx.z;
  const int b = bh >> 4, h = bh & 15;
  const bf16* src = qkv + (size_t)b * S_ * (3 * E_) + 2 * E_ + h * D_;
#pragma unroll
  for (int j = 0; j < 4; ++j)
    t[ty + 8 * j][tx] = src[(size_t)(s0 + ty + 8 * j) * (3 * E_) + d0 + tx];
  __syncthreads();
  bf16* dst = vt + (size_t)bh * D_ * S_;
#pragma unroll
  for (int j = 0; j < 4; ++j)
    dst[(size_t)(d0 + ty + 8 * j) * S_ + s0 + tx] = t[tx][ty + 8 * j];
}

// ---------------------------------------------------------------------------
// GEMM: C[M,N] = A[M,K] @ Bt[N,K]^T, bf16 in, OutT out, fp32 accum.
// 128x128 tile, BK=64, 4 waves (2x2 of 64x64), 16x16x32 MFMA. m97 structure.
// ---------------------------------------------------------------------------
template <typename OutT>
__global__ __launch_bounds__(256) void gemm_bt128(
    OutT* __restrict__ C, const bf16* __restrict__ A, const bf16* __restrict__ Bt,
    int M, int N, int K) {
  __shared__ alignas(16) bf16 sA[8192];  // 16KB
  __shared__ alignas(16) bf16 sB[8192];  // 16KB
  const int tid = threadIdx.x;
  const int lane = tid & 63;
  const int w = tid >> 6;
  const int wr = (w >> 1) * 64, wc = (w & 1) * 64;
  const int l15 = lane & 15, l4 = lane >> 4;
  const int m0 = blockIdx.x * 128;
  const int n0 = blockIdx.y * 128;

  floatx4 acc[4][4];
#pragma unroll
  for (int i = 0; i < 4; ++i)
#pragma unroll
    for (int j = 0; j < 4; ++j) acc[i][j] = (floatx4){0.f, 0.f, 0.f, 0.f};

  for (int k0 = 0; k0 < K; k0 += 64) {
#pragma unroll
    for (int j = 0; j < 4; ++j) {
      const int cb = (w * 4 + j) * 64;       // chunk base for this instr
      const int kg = cb >> 7, rb = cb & 127; // kgroup, row base
      async16(A + (size_t)(m0 + rb + lane) * K + k0 + kg * 8, &sA[cb * 8]);
      async16(Bt + (size_t)(n0 + rb + lane) * K + k0 + kg * 8, &sB[cb * 8]);
    }
    __syncthreads();
#pragma unroll
    for (int ks = 0; ks < 2; ++ks) {
      bf16x8 af[4], bfr[4];
#pragma unroll
      for (int t = 0; t < 4; ++t)
        af[t] = *(const bf16x8*)&sA[((ks * 4 + l4) * 128 + wr + t * 16 + l15) * 8];
#pragma unroll
      for (int t = 0; t < 4; ++t)
        bfr[t] = *(const bf16x8*)&sB[((ks * 4 + l4) * 128 + wc + t * 16 + l15) * 8];
#pragma unroll
      for (int i = 0; i < 4; ++i)
#pragma unroll
        for (int j = 0; j < 4; ++j)
          acc[i][j] = __builtin_amdgcn_mfma_f32_16x16x32_bf16(af[i], bfr[j],
                                                              acc[i][j], 0, 0, 0);
    }
    __syncthreads();
  }
  // epilogue: C/D layout col=lane&15, row=(lane>>4)*4+reg
#pragma unroll
  for (int i = 0; i < 4; ++i)
#pragma unroll
    for (int j = 0; j < 4; ++j)
#pragma unroll
      for (int r = 0; r < 4; ++r) {
        const int row = m0 + wr + i * 16 + l4 * 4 + r;
        const int col = n0 + wc + j * 16 + l15;
        C[(size_t)row * N + col] = (OutT)acc[i][j][r];
      }
}

// ---------------------------------------------------------------------------
// Flash attention. grid (S/128=16, B*H=32), block 256 (4 waves).
// Wave w owns q-rows [w*32, w*32+32): all softmax row stats are intra-wave.
// ---------------------------------------------------------------------------
__global__ __launch_bounds__(256) void attn_flash(
    bf16* __restrict__ attn, const bf16* __restrict__ qkv,
    const bf16* __restrict__ vt) {
  __shared__ alignas(16) bf16 sK[8192];      // 16KB  chunk (kg<8, key<128)
  __shared__ alignas(16) bf16 sV[8192];      // 16KB  chunk (kg<16, dim<64)
  __shared__ alignas(16) bf16 sP[4][4096];   // 8KB/wave, chunk (kg<16, row<32)
  const int tid = threadIdx.x;
  const int lane = tid & 63;
  const int w = tid >> 6;
  const int l15 = lane & 15, l4 = lane >> 4;
  const int q0 = blockIdx.x * 128;
  const int bh = blockIdx.y;
  const int b = bh >> 4, h = bh & 15;
  const size_t row0 = (size_t)b * S_ * (3 * E_);

  // Q fragments in registers: A-layout A[m=lane&15][k=(lane>>4)*8+j]
  bf16x8 qf[2][2];
#pragma unroll
  for (int rt = 0; rt < 2; ++rt)
#pragma unroll
    for (int ks = 0; ks < 2; ++ks)
      qf[rt][ks] = *(const bf16x8*)(qkv + row0 +
          (size_t)(q0 + w * 32 + rt * 16 + l15) * (3 * E_) +
          h * D_ + ks * 32 + l4 * 8);

  floatx4 O[2][4];
#pragma unroll
  for (int i = 0; i < 2; ++i)
#pragma unroll
    for (int j = 0; j < 4; ++j) O[i][j] = (floatx4){0.f, 0.f, 0.f, 0.f};
  float m_r[2][4], l_r[2][4];
#pragma unroll
  for (int i = 0; i < 2; ++i)
#pragma unroll
    for (int r = 0; r < 4; ++r) { m_r[i][r] = -1e30f; l_r[i][r] = 0.f; }

  for (int kv0 = 0; kv0 < S_; kv0 += 128) {
    // stage K tile + V^T tile (4 instrs each per wave)
#pragma unroll
    for (int j = 0; j < 4; ++j) {
      const int cb = (w * 4 + j) * 64;
      // K: chunk c -> kg=c>>7, keyrow=c&127
      async16(qkv + row0 + (size_t)(kv0 + (cb & 127) + lane) * (3 * E_) +
                  E_ + h * D_ + (cb >> 7) * 8,
              &sK[cb * 8]);
      // V^T: chunk c -> kg=c>>6 (=w*4+j), dim=c&63 (=lane)
      async16(vt + ((size_t)bh * D_ + lane) * S_ + kv0 + (w * 4 + j) * 8,
              &sV[cb * 8]);
    }
    __syncthreads();

    // ---- QK^T ----
    floatx4 sc[2][8];
#pragma unroll
    for (int i = 0; i < 2; ++i)
#pragma unroll
      for (int j = 0; j < 8; ++j) sc[i][j] = (floatx4){0.f, 0.f, 0.f, 0.f};
#pragma unroll
    for (int ks = 0; ks < 2; ++ks) {
      bf16x8 kf[8];
#pragma unroll
      for (int ct = 0; ct < 8; ++ct)
        kf[ct] = *(const bf16x8*)&sK[((ks * 4 + l4) * 128 + ct * 16 + l15) * 8];
#pragma unroll
      for (int rt = 0; rt < 2; ++rt)
#pragma unroll
        for (int ct = 0; ct < 8; ++ct)
          sc[rt][ct] = __builtin_amdgcn_mfma_f32_16x16x32_bf16(
              qf[rt][ks], kf[ct], sc[rt][ct], 0, 0, 0);
    }

    // ---- online softmax (rows owned intra-wave) ----
#pragma unroll
    for (int rt = 0; rt < 2; ++rt)
#pragma unroll
      for (int ct = 0; ct < 8; ++ct) sc[rt][ct] *= 0.125f;  // 1/sqrt(64)

#pragma unroll
    for (int rt = 0; rt < 2; ++rt)
#pragma unroll
      for (int r = 0; r < 4; ++r) {
        float mx = -1e30f;
#pragma unroll
        for (int ct = 0; ct < 8; ++ct) mx = fmaxf(mx, sc[rt][ct][r]);
        mx = fmaxf(mx, __shfl_xor(mx, 1));
        mx = fmaxf(mx, __shfl_xor(mx, 2));
        mx = fmaxf(mx, __shfl_xor(mx, 4));
        mx = fmaxf(mx, __shfl_xor(mx, 8));
        const float mnew = fmaxf(m_r[rt][r], mx);
        const float alpha = __expf(m_r[rt][r] - mnew);
        m_r[rt][r] = mnew;
        float rs = 0.f;
#pragma unroll
        for (int ct = 0; ct < 8; ++ct) {
          const float p = __expf(sc[rt][ct][r] - mnew);
          sc[rt][ct][r] = p;
          rs += p;
        }
        rs += __shfl_xor(rs, 1);
        rs += __shfl_xor(rs, 2);
        rs += __shfl_xor(rs, 4);
        rs += __shfl_xor(rs, 8);
        l_r[rt][r] = l_r[rt][r] * alpha + rs;
#pragma unroll
        for (int dt = 0; dt < 4; ++dt) O[rt][dt][r] *= alpha;
      }

    // ---- P (C-layout) -> per-wave LDS (A-layout readable, kgroup-major) ----
#pragma unroll
    for (int rt = 0; rt < 2; ++rt)
#pragma unroll
      for (int ct = 0; ct < 8; ++ct)
#pragma unroll
        for (int r = 0; r < 4; ++r) {
          const int prow = rt * 16 + l4 * 4 + r;
          const int col = ct * 16 + l15;
          sP[w][((col >> 3) * 32 + prow) * 8 + (col & 7)] = (bf16)sc[rt][ct][r];
        }
    __syncthreads();  // order P stores vs vector reloads

    // ---- PV ----
#pragma unroll
    for (int ks = 0; ks < 4; ++ks) {
      bf16x8 pf[2], vf[4];
#pragma unroll
      for (int rt = 0; rt < 2; ++rt)
        pf[rt] = *(const bf16x8*)&sP[w][((ks * 4 + l4) * 32 + rt * 16 + l15) * 8];
#pragma unroll
      for (int dt = 0; dt < 4; ++dt)
        vf[dt] = *(const bf16x8*)&sV[((ks * 4 + l4) * 64 + dt * 16 + l15) * 8];
#pragma unroll
      for (int rt = 0; rt < 2; ++rt)
#pragma unroll
        for (int dt = 0; dt < 4; ++dt)
          O[rt][dt] = __builtin_amdgcn_mfma_f32_16x16x32_bf16(
              pf[rt], vf[dt], O[rt][dt], 0, 0, 0);
    }
    __syncthreads();  // protect sK/sV before next stage
  }

  // epilogue: attn[(b*S + row)*E + h*D + dim] = O / l
#pragma unroll
  for (int rt = 0; rt < 2; ++rt)
#pragma unroll
    for (int dt = 0; dt < 4; ++dt)
#pragma unroll
      for (int r = 0; r < 4; ++r) {
        const int row = q0 + w * 32 + rt * 16 + l4 * 4 + r;
        const int col = h * D_ + dt * 16 + l15;
        attn[((size_t)b * S_ + row) * E_ + col] =
            (bf16)(O[rt][dt][r] / l_r[rt][r]);
      }
}

// ---------------------------------------------------------------------------
extern "C" void kernel_launch(void* const* d_in, const int* in_sizes, int n_in,
                              void* d_out, int out_size, void* d_ws, size_t ws_size,
                              hipStream_t stream) {
  const float* x = (const float*)d_in[0];      // (B,S,E) fp32
  const float* wqkv = (const float*)d_in[1];   // (E,3E)  fp32
  const float* wout = (const float*)d_in[2];   // (E,E)   fp32
  float* out = (float*)d_out;                  // (B,S,E) fp32

  bf16* ws = (bf16*)d_ws;
  bf16* xb = ws;                                    // 4096 x 1024
  bf16* qkv = xb + (size_t)4096 * 1024;             // 4096 x 3072
  bf16* wqkvT = qkv + (size_t)4096 * 3072;          // 3072 x 1024
  bf16* woutT = wqkvT + (size_t)3072 * 1024;        // 1024 x 1024
  bf16* vt = woutT + (size_t)1024 * 1024;           // (B*H) x 64 x 2048
  bf16* attn = vt + (size_t)B_ * H_ * D_ * S_;      // 4096 x 1024

  cvt_f32_bf16<<<dim3(4096 * 1024 / 4 / 256), 256, 0, stream>>>(
      xb, x, 4096 * 1024 / 4);
  transpose_f32_bf16<<<dim3(3 * E_ / 32, E_ / 32), 256, 0, stream>>>(
      wqkvT, wqkv, E_, 3 * E_);
  transpose_f32_bf16<<<dim3(E_ / 32, E_ / 32), 256, 0, stream>>>(
      woutT, wout, E_, E_);
  gemm_bt128<bf16><<<dim3(32, 24), 256, 0, stream>>>(qkv, xb, wqkvT, 4096, 3 * E_, E_);
  vt_repack<<<dim3(D_ / 32, S_ / 32, B_ * H_), 256, 0, stream>>>(vt, qkv);
  attn_flash<<<dim3(S_ / 128, B_ * H_), 256, 0, stream>>>(attn, qkv, vt);
  gemm_bt128<float><<<dim3(32, 8), 256, 0, stream>>>(out, attn, woutT, 4096, E_, E_);
}